// Round 3
// baseline (104.294 us; speedup 1.0000x reference)
//
#include <hip/hip_runtime.h>
#include <hip/hip_bf16.h>
#include <math.h>

#define NF    50              // n_frequencies
#define DEMB  10              // embedding dim
#define W1G   (4 * NF * DEMB) // 2000 floats of w1 per gene
#define MAXG  512             // max genes supported by sort path

#define HTPB  256
#define HCHUNK 2048
#define HFPT  (HCHUNK / HTPB) // 8 fragments per thread in hist/scatter

// ---------------------------------------------------------------------------
// K1: per-block private histogram (no global atomics) + out init with b2
// ---------------------------------------------------------------------------
__global__ __launch_bounds__(HTPB) void hist_init_k(
    const int* __restrict__ gm, int n_frag, int n_genes,
    int* __restrict__ counts_mat,                 // [gridDim.x][MAXG]
    float* __restrict__ out, const float* __restrict__ b2,
    const int* __restrict__ genes_oi, int gene_n, int total)
{
    __shared__ int lcnt[MAXG];
    for (int t = threadIdx.x; t < MAXG; t += HTPB) lcnt[t] = 0;
    __syncthreads();

    int base = blockIdx.x * HCHUNK;
#pragma unroll
    for (int j = 0; j < HFPT; ++j) {
        int f = base + j * HTPB + (int)threadIdx.x;
        if (f < n_frag) atomicAdd(&lcnt[gm[f]], 1);
    }

    // init out with broadcast b2 (grid-stride; independent of hist)
    int nthreads = gridDim.x * HTPB;
    for (int i = blockIdx.x * HTPB + (int)threadIdx.x; i < total; i += nthreads) {
        int col = (int)((unsigned)i % (unsigned)gene_n);
        out[i] = b2[genes_oi[col]];
    }

    __syncthreads();
    int* row = counts_mat + (size_t)blockIdx.x * MAXG;
    for (int t = threadIdx.x; t < MAXG; t += HTPB) row[t] = lcnt[t];
}

// ---------------------------------------------------------------------------
// K2: reduce count matrix + exclusive scan (1 block, MAXG threads)
// ---------------------------------------------------------------------------
__global__ void scan_k(const int* __restrict__ counts_mat, int nblk,
                       int* __restrict__ offsets, int* __restrict__ cursor, int n_genes)
{
    __shared__ int buf[MAXG];
    int tid = threadIdx.x;
    int s = 0;
    for (int b = 0; b < nblk; ++b) s += counts_mat[(size_t)b * MAXG + tid];
    buf[tid] = s;
    __syncthreads();
    for (int d = 1; d < MAXG; d <<= 1) {
        int t = (tid >= d) ? buf[tid - d] : 0;
        __syncthreads();
        buf[tid] += t;
        __syncthreads();
    }
    if (tid < n_genes) {
        int incl = buf[tid];
        offsets[tid + 1] = incl;
        cursor[tid] = incl - s;   // exclusive prefix
    }
    if (tid == 0) offsets[0] = 0;
}

// ---------------------------------------------------------------------------
// K3: scatter packed records into gene-sorted compact order.
// LDS atomics assign local ranks; <=n_genes returning global atomics/block.
// Records: xs[2*pos+c] = coordinate c, garr[pos] = gene, bins[pos] = out bin.
// ---------------------------------------------------------------------------
__global__ __launch_bounds__(HTPB) void scatter_k(
    const int* __restrict__ gm, const float* __restrict__ coords,
    const int* __restrict__ lcg, int* __restrict__ cursor,
    float* __restrict__ xs, int* __restrict__ garr, int* __restrict__ bins,
    int n_frag, int n_genes)
{
    __shared__ int lcnt[MAXG];
    __shared__ int lbase[MAXG];
    for (int t = threadIdx.x; t < MAXG; t += HTPB) lcnt[t] = 0;
    __syncthreads();

    int base = blockIdx.x * HCHUNK;
    int g[HFPT], lr[HFPT];
#pragma unroll
    for (int j = 0; j < HFPT; ++j) {
        int f = base + j * HTPB + (int)threadIdx.x;
        if (f < n_frag) {
            g[j]  = gm[f];
            lr[j] = atomicAdd(&lcnt[g[j]], 1);
        } else {
            g[j] = -1;
        }
    }
    __syncthreads();
    for (int t = threadIdx.x; t < MAXG; t += HTPB) {
        int c = lcnt[t];
        lbase[t] = c ? atomicAdd(&cursor[t], c) : 0;
    }
    __syncthreads();
#pragma unroll
    for (int j = 0; j < HFPT; ++j) {
        if (g[j] >= 0) {
            int f = base + j * HTPB + (int)threadIdx.x;
            int pos = lbase[g[j]] + lr[j];
            float2 xy = ((const float2*)coords)[f];
            xs[2 * pos + 0] = xy.x;
            xs[2 * pos + 1] = xy.y;
            garr[pos] = g[j];
            bins[pos] = lcg[f];
        }
    }
}

// ---------------------------------------------------------------------------
// K4: main — 2 threads per fragment (one coordinate each), flat over the
// sorted compact array. Wave lanes share the gene (long same-gene runs) so
// w1 loads coalesce to 1-2 lines per instruction.
// ---------------------------------------------------------------------------
__global__ __launch_bounds__(256) void main_k(
    const float* __restrict__ w1, const float* __restrict__ b1,
    const float* __restrict__ w2, const int* __restrict__ genes_oi,
    const float* __restrict__ xs, const int* __restrict__ garr,
    const int* __restrict__ bins, float* __restrict__ out,
    int gene_n, int n_frag)
{
    __shared__ float fr[NF];
    if (threadIdx.x < NF) {
        float ex = (-2.0f * (float)(threadIdx.x + 1) / (float)NF) * 9.965784284662087f;
        fr[threadIdx.x] = exp2f(ex) * 0.15915494309189535f;  // base/(2*pi): revolutions
    }
    __syncthreads();

    int t = blockIdx.x * 256 + (int)threadIdx.x;
    int idx = t >> 1;
    if (idx >= n_frag) return;
    int c = t & 1;                         // which coordinate this thread owns

    int g = garr[idx];                     // pairs share -> coalesced
    float x = xs[t];                       // perfectly coalesced 4B
    const float* wrow = w1 + (size_t)g * W1G + c * (W1G / 2);

    float h[DEMB];
    if (c == 0) {
        const float* b1row = b1 + (size_t)g * DEMB;
#pragma unroll
        for (int d = 0; d < DEMB; ++d) h[d] = b1row[d];
    } else {
#pragma unroll
        for (int d = 0; d < DEMB; ++d) h[d] = 0.0f;
    }

#pragma unroll 2
    for (int i = 0; i < NF; ++i) {
        float fv = fr[i];
        float r = x * fv; r -= rintf(r);   // revolutions in [-0.5, 0.5]
        float s  = __builtin_amdgcn_sinf(r);
        float co = __builtin_amdgcn_cosf(r);
        const float* base = wrow + i * (2 * DEMB);   // rows 2i (sin), 2i+1 (cos)
#pragma unroll
        for (int d = 0; d < DEMB; ++d) {
            h[d] += s * base[d];
            h[d] += co * base[DEMB + d];
        }
    }

    // combine the two coordinate halves
#pragma unroll
    for (int d = 0; d < DEMB; ++d) h[d] += __shfl_xor(h[d], 1);

    if (c == 0) {
        int bin = bins[idx];
        int col = (int)((unsigned)bin % (unsigned)gene_n);
        const float* w2row = w2 + (size_t)genes_oi[col] * DEMB;
        float sum = 0.0f;
#pragma unroll
        for (int d = 0; d < DEMB; ++d) {
            float sg = 1.0f / (1.0f + __expf(-h[d]));
            sum += sg * w2row[d];
        }
        atomicAdd(&out[bin], sum);
    }
}

// ---------------------------------------------------------------------------
// Fallback (workspace too small): one thread per fragment, non-uniform gene
// ---------------------------------------------------------------------------
__global__ __launch_bounds__(256) void frag_naive_k(
    const float* __restrict__ coords, const float* __restrict__ w1,
    const float* __restrict__ b1, const float* __restrict__ w2,
    const float* __restrict__ b2, const int* __restrict__ gm,
    const int* __restrict__ lcg, const int* __restrict__ genes_oi,
    float* __restrict__ out, int gene_n, int n_frag, int total)
{
    __shared__ float fr[NF];
    if (threadIdx.x < NF) {
        float ex = (-2.0f * (float)(threadIdx.x + 1) / (float)NF) * 9.965784284662087f;
        fr[threadIdx.x] = exp2f(ex) * 0.15915494309189535f;
    }
    __syncthreads();

    int f = blockIdx.x * blockDim.x + threadIdx.x;
    // init out first pass (separate launch handles ordering via two kernels in caller)
    if (f >= n_frag) return;
    int g = gm[f];
    const float* wrow  = w1 + (size_t)g * W1G;
    const float* b1row = b1 + (size_t)g * DEMB;
    float x0 = coords[2 * f + 0];
    float x1 = coords[2 * f + 1];

    float h[DEMB];
#pragma unroll
    for (int d = 0; d < DEMB; ++d) h[d] = b1row[d];
#pragma unroll 2
    for (int i = 0; i < NF; ++i) {
        float fv = fr[i];
        float r0 = x0 * fv; r0 -= rintf(r0);
        float r1 = x1 * fv; r1 -= rintf(r1);
        float s0 = __builtin_amdgcn_sinf(r0), c0 = __builtin_amdgcn_cosf(r0);
        float s1 = __builtin_amdgcn_sinf(r1), c1 = __builtin_amdgcn_cosf(r1);
        const float* wa = wrow + (2 * i) * DEMB;
        const float* wb = wrow + (2 * NF + 2 * i) * DEMB;
#pragma unroll
        for (int d = 0; d < DEMB; ++d) {
            h[d] += s0 * wa[d] + c0 * wa[DEMB + d] + s1 * wb[d] + c1 * wb[DEMB + d];
        }
    }
    int bin = lcg[f];
    int col = (int)((unsigned)bin % (unsigned)gene_n);
    const float* w2row = w2 + (size_t)genes_oi[col] * DEMB;
    float sum = 0.0f;
#pragma unroll
    for (int d = 0; d < DEMB; ++d) {
        float sg = 1.0f / (1.0f + __expf(-h[d]));
        sum += sg * w2row[d];
    }
    atomicAdd(&out[bin], sum);
}

__global__ void init_out_k(float* __restrict__ out, const float* __restrict__ b2,
                           const int* __restrict__ genes_oi, int gene_n, int total)
{
    int i = blockIdx.x * blockDim.x + threadIdx.x;
    if (i < total) {
        int col = (int)((unsigned)i % (unsigned)gene_n);
        out[i] = b2[genes_oi[col]];
    }
}

// ---------------------------------------------------------------------------
extern "C" void kernel_launch(void* const* d_in, const int* in_sizes, int n_in,
                              void* d_out, int out_size, void* d_ws, size_t ws_size,
                              hipStream_t stream)
{
    const float* coords   = (const float*)d_in[0];
    const float* w1       = (const float*)d_in[1];
    const float* b1       = (const float*)d_in[2];
    const float* w2       = (const float*)d_in[3];
    const float* b2       = (const float*)d_in[4];
    const int*   gm       = (const int*)d_in[5];
    const int*   lcg      = (const int*)d_in[6];
    const int*   genes_oi = (const int*)d_in[7];

    int n_frag  = in_sizes[5];
    int n_genes = in_sizes[4];
    int gene_n  = in_sizes[7];
    int total   = out_size;
    float* out  = (float*)d_out;

    int nblk = (n_frag + HCHUNK - 1) / HCHUNK;

    // workspace layout
    int* counts_mat = (int*)d_ws;                         // [nblk][MAXG]
    int* offsets    = counts_mat + (size_t)nblk * MAXG;   // [MAXG+1]
    int* cursor     = offsets + (MAXG + 1);               // [MAXG]
    float* xs       = (float*)(cursor + MAXG);            // [2*n_frag]
    int* garr       = (int*)(xs + 2 * (size_t)n_frag);    // [n_frag]
    int* bins       = garr + n_frag;                      // [n_frag]
    size_t need = ((size_t)nblk * MAXG + (MAXG + 1) + MAXG
                   + 2 * (size_t)n_frag + 2 * (size_t)n_frag) * sizeof(int);

    bool use_sorted = (ws_size >= need) && (n_genes <= MAXG);
    if (use_sorted) {
        hist_init_k<<<nblk, HTPB, 0, stream>>>(gm, n_frag, n_genes, counts_mat,
                                               out, b2, genes_oi, gene_n, total);
        scan_k<<<1, MAXG, 0, stream>>>(counts_mat, nblk, offsets, cursor, n_genes);
        scatter_k<<<nblk, HTPB, 0, stream>>>(gm, coords, lcg, cursor,
                                             xs, garr, bins, n_frag, n_genes);
        int mblk = (2 * n_frag + 255) / 256;
        main_k<<<mblk, 256, 0, stream>>>(w1, b1, w2, genes_oi, xs, garr, bins,
                                         out, gene_n, n_frag);
    } else {
        init_out_k<<<(total + 255) / 256, 256, 0, stream>>>(out, b2, genes_oi, gene_n, total);
        frag_naive_k<<<(n_frag + 255) / 256, 256, 0, stream>>>(coords, w1, b1, w2, b2, gm, lcg,
                                                               genes_oi, out, gene_n, n_frag, total);
    }
}

// Round 4
// 59.042 us; speedup vs baseline: 1.7664x; 1.7664x over previous
//
#include <hip/hip_runtime.h>
#include <hip/hip_bf16.h>
#include <math.h>

#define NF    50              // n_frequencies
#define DEMB  10              // embedding dim
#define W1G   (4 * NF * DEMB) // 2000 floats of w1 per gene
#define MAXG  512             // max genes supported by sort path

#define HTPB  256
#define HCHUNK 2048
#define HFPT  (HCHUNK / HTPB) // 8 fragments per thread in hist/scatter

#define SPLIT 2               // blocks per gene in main kernel

// ---------------------------------------------------------------------------
// K1: per-block private histogram (no global atomics) + out init with b2
// ---------------------------------------------------------------------------
__global__ __launch_bounds__(HTPB) void hist_init_k(
    const int* __restrict__ gm, int n_frag, int n_genes,
    int* __restrict__ counts_mat,                 // [gridDim.x][MAXG]
    float* __restrict__ out, const float* __restrict__ b2,
    const int* __restrict__ genes_oi, int gene_n, int total)
{
    __shared__ int lcnt[MAXG];
    for (int t = threadIdx.x; t < MAXG; t += HTPB) lcnt[t] = 0;
    __syncthreads();

    int base = blockIdx.x * HCHUNK;
#pragma unroll
    for (int j = 0; j < HFPT; ++j) {
        int f = base + j * HTPB + (int)threadIdx.x;
        if (f < n_frag) atomicAdd(&lcnt[gm[f]], 1);
    }

    // init out with broadcast b2 (grid-stride; independent of hist)
    int nthreads = gridDim.x * HTPB;
    for (int i = blockIdx.x * HTPB + (int)threadIdx.x; i < total; i += nthreads) {
        int col = (int)((unsigned)i % (unsigned)gene_n);
        out[i] = b2[genes_oi[col]];
    }

    __syncthreads();
    int* row = counts_mat + (size_t)blockIdx.x * MAXG;
    for (int t = threadIdx.x; t < MAXG; t += HTPB) row[t] = lcnt[t];
}

// ---------------------------------------------------------------------------
// K2: reduce count matrix + exclusive scan (1 block, MAXG threads)
// ---------------------------------------------------------------------------
__global__ void scan_k(const int* __restrict__ counts_mat, int nblk,
                       int* __restrict__ offsets, int* __restrict__ cursor, int n_genes)
{
    __shared__ int buf[MAXG];
    int tid = threadIdx.x;
    int s = 0;
    for (int b = 0; b < nblk; ++b) s += counts_mat[(size_t)b * MAXG + tid];
    buf[tid] = s;
    __syncthreads();
    for (int d = 1; d < MAXG; d <<= 1) {
        int t = (tid >= d) ? buf[tid - d] : 0;
        __syncthreads();
        buf[tid] += t;
        __syncthreads();
    }
    if (tid < n_genes) {
        int incl = buf[tid];
        offsets[tid + 1] = incl;
        cursor[tid] = incl - s;   // exclusive prefix
    }
    if (tid == 0) offsets[0] = 0;
}

// ---------------------------------------------------------------------------
// K3: scatter packed records (coords, bin) into gene-sorted compact order.
// LDS atomics assign local ranks; <=n_genes returning global atomics/block.
// ---------------------------------------------------------------------------
__global__ __launch_bounds__(HTPB) void scatter_k(
    const int* __restrict__ gm, const float* __restrict__ coords,
    const int* __restrict__ lcg, int* __restrict__ cursor,
    float* __restrict__ xs, int* __restrict__ bins,
    int n_frag, int n_genes)
{
    __shared__ int lcnt[MAXG];
    __shared__ int lbase[MAXG];
    for (int t = threadIdx.x; t < MAXG; t += HTPB) lcnt[t] = 0;
    __syncthreads();

    int base = blockIdx.x * HCHUNK;
    int g[HFPT], lr[HFPT];
#pragma unroll
    for (int j = 0; j < HFPT; ++j) {
        int f = base + j * HTPB + (int)threadIdx.x;
        if (f < n_frag) {
            g[j]  = gm[f];
            lr[j] = atomicAdd(&lcnt[g[j]], 1);
        } else {
            g[j] = -1;
        }
    }
    __syncthreads();
    for (int t = threadIdx.x; t < MAXG; t += HTPB) {
        int c = lcnt[t];
        lbase[t] = c ? atomicAdd(&cursor[t], c) : 0;
    }
    __syncthreads();
#pragma unroll
    for (int j = 0; j < HFPT; ++j) {
        if (g[j] >= 0) {
            int f = base + j * HTPB + (int)threadIdx.x;
            int pos = lbase[g[j]] + lr[j];
            float2 xy = ((const float2*)coords)[f];
            xs[2 * pos + 0] = xy.x;
            xs[2 * pos + 1] = xy.y;
            bins[pos] = lcg[f];
        }
    }
}

// ---------------------------------------------------------------------------
// K4: main — block-per-gene (SPLIT blocks/gene). w1 row staged in LDS in a
// freq-major padded layout so the inner loop is broadcast ds_read_b128 + FMA.
// lw[i][slot][0..11]: slot 0 = sin row (2i), 1 = cos row (2i+1) of coord 0;
//                     slot 2 = sin row (2NF+2i), 3 = cos row (2NF+2i+1) of coord 1.
// ---------------------------------------------------------------------------
__global__ __launch_bounds__(256) void main_k(
    const float* __restrict__ w1, const float* __restrict__ b1,
    const float* __restrict__ w2, const int* __restrict__ genes_oi,
    const float* __restrict__ xs, const int* __restrict__ bins,
    const int* __restrict__ offsets, float* __restrict__ out, int gene_n)
{
    __shared__ float fr[NF];
    __shared__ __align__(16) float lw[NF][4][12];
    __shared__ float lb1[DEMB];

    int g    = blockIdx.x / SPLIT;
    int part = blockIdx.x % SPLIT;
    const float* wrow = w1 + (size_t)g * W1G;

    if (threadIdx.x < NF) {
        float ex = (-2.0f * (float)(threadIdx.x + 1) / (float)NF) * 9.965784284662087f;
        fr[threadIdx.x] = exp2f(ex) * 0.15915494309189535f;  // base/(2*pi): revolutions
    }
    if (threadIdx.x < DEMB) lb1[threadIdx.x] = b1[(size_t)g * DEMB + threadIdx.x];

    // stage + permute + pad the gene's w1 row: 2400 floats
    for (int k = threadIdx.x; k < NF * 4 * 12; k += 256) {
        int i    = k / 48;
        int rem  = k - i * 48;
        int slot = rem / 12;
        int d    = rem - slot * 12;
        float v = 0.0f;
        if (d < DEMB) {
            int s = (slot < 2) ? (2 * i + slot) : (2 * NF + 2 * i + (slot - 2));
            v = wrow[s * DEMB + d];
        }
        (&lw[0][0][0])[k] = v;
    }
    __syncthreads();

    int s0 = offsets[g], e0 = offsets[g + 1];
    int n = e0 - s0;
    int chunk = (n + SPLIT - 1) / SPLIT;
    int start = s0 + part * chunk;
    int end = (start + chunk < e0) ? (start + chunk) : e0;

    for (int idx = start + (int)threadIdx.x; idx < end; idx += 256) {
        float2 xy = ((const float2*)xs)[idx];

        float4 h0 = make_float4(lb1[0], lb1[1], lb1[2], lb1[3]);
        float4 h1 = make_float4(lb1[4], lb1[5], lb1[6], lb1[7]);
        float2 h2 = make_float2(lb1[8], lb1[9]);

#pragma unroll 2
        for (int i = 0; i < NF; ++i) {
            float fv = fr[i];
            float r0 = xy.x * fv; r0 -= rintf(r0);
            float r1 = xy.y * fv; r1 -= rintf(r1);
            float v0 = __builtin_amdgcn_sinf(r0);
            float v1 = __builtin_amdgcn_cosf(r0);
            float v2 = __builtin_amdgcn_sinf(r1);
            float v3 = __builtin_amdgcn_cosf(r1);
            float vv[4] = {v0, v1, v2, v3};
#pragma unroll
            for (int slot = 0; slot < 4; ++slot) {
                float sv = vv[slot];
                const float4* bp = (const float4*)(&lw[i][slot][0]);
                float4 a = bp[0];
                float4 b = bp[1];
                float2 c = *(const float2*)(&lw[i][slot][8]);
                h0.x += sv * a.x; h0.y += sv * a.y; h0.z += sv * a.z; h0.w += sv * a.w;
                h1.x += sv * b.x; h1.y += sv * b.y; h1.z += sv * b.z; h1.w += sv * b.w;
                h2.x += sv * c.x; h2.y += sv * c.y;
            }
        }

        int bin = bins[idx];
        int col = (int)((unsigned)bin % (unsigned)gene_n);
        const float* w2row = w2 + (size_t)genes_oi[col] * DEMB;
        float hh[DEMB] = {h0.x, h0.y, h0.z, h0.w, h1.x, h1.y, h1.z, h1.w, h2.x, h2.y};
        float sum = 0.0f;
#pragma unroll
        for (int d = 0; d < DEMB; ++d) {
            float sg = 1.0f / (1.0f + __expf(-hh[d]));
            sum += sg * w2row[d];
        }
        atomicAdd(&out[bin], sum);
    }
}

// ---------------------------------------------------------------------------
// Fallback (workspace too small): one thread per fragment, non-uniform gene
// ---------------------------------------------------------------------------
__global__ __launch_bounds__(256) void frag_naive_k(
    const float* __restrict__ coords, const float* __restrict__ w1,
    const float* __restrict__ b1, const float* __restrict__ w2,
    const int* __restrict__ gm, const int* __restrict__ lcg,
    const int* __restrict__ genes_oi, float* __restrict__ out,
    int gene_n, int n_frag)
{
    __shared__ float fr[NF];
    if (threadIdx.x < NF) {
        float ex = (-2.0f * (float)(threadIdx.x + 1) / (float)NF) * 9.965784284662087f;
        fr[threadIdx.x] = exp2f(ex) * 0.15915494309189535f;
    }
    __syncthreads();

    int f = blockIdx.x * blockDim.x + threadIdx.x;
    if (f >= n_frag) return;
    int g = gm[f];
    const float* wrow  = w1 + (size_t)g * W1G;
    const float* b1row = b1 + (size_t)g * DEMB;
    float x0 = coords[2 * f + 0];
    float x1 = coords[2 * f + 1];

    float h[DEMB];
#pragma unroll
    for (int d = 0; d < DEMB; ++d) h[d] = b1row[d];
#pragma unroll 2
    for (int i = 0; i < NF; ++i) {
        float fv = fr[i];
        float r0 = x0 * fv; r0 -= rintf(r0);
        float r1 = x1 * fv; r1 -= rintf(r1);
        float s0 = __builtin_amdgcn_sinf(r0), c0 = __builtin_amdgcn_cosf(r0);
        float s1 = __builtin_amdgcn_sinf(r1), c1 = __builtin_amdgcn_cosf(r1);
        const float* wa = wrow + (2 * i) * DEMB;
        const float* wb = wrow + (2 * NF + 2 * i) * DEMB;
#pragma unroll
        for (int d = 0; d < DEMB; ++d) {
            h[d] += s0 * wa[d] + c0 * wa[DEMB + d] + s1 * wb[d] + c1 * wb[DEMB + d];
        }
    }
    int bin = lcg[f];
    int col = (int)((unsigned)bin % (unsigned)gene_n);
    const float* w2row = w2 + (size_t)genes_oi[col] * DEMB;
    float sum = 0.0f;
#pragma unroll
    for (int d = 0; d < DEMB; ++d) {
        float sg = 1.0f / (1.0f + __expf(-h[d]));
        sum += sg * w2row[d];
    }
    atomicAdd(&out[bin], sum);
}

__global__ void init_out_k(float* __restrict__ out, const float* __restrict__ b2,
                           const int* __restrict__ genes_oi, int gene_n, int total)
{
    int i = blockIdx.x * blockDim.x + threadIdx.x;
    if (i < total) {
        int col = (int)((unsigned)i % (unsigned)gene_n);
        out[i] = b2[genes_oi[col]];
    }
}

// ---------------------------------------------------------------------------
extern "C" void kernel_launch(void* const* d_in, const int* in_sizes, int n_in,
                              void* d_out, int out_size, void* d_ws, size_t ws_size,
                              hipStream_t stream)
{
    const float* coords   = (const float*)d_in[0];
    const float* w1       = (const float*)d_in[1];
    const float* b1       = (const float*)d_in[2];
    const float* w2       = (const float*)d_in[3];
    const float* b2       = (const float*)d_in[4];
    const int*   gm       = (const int*)d_in[5];
    const int*   lcg      = (const int*)d_in[6];
    const int*   genes_oi = (const int*)d_in[7];

    int n_frag  = in_sizes[5];
    int n_genes = in_sizes[4];
    int gene_n  = in_sizes[7];
    int total   = out_size;
    float* out  = (float*)d_out;

    int nblk = (n_frag + HCHUNK - 1) / HCHUNK;

    // workspace layout
    int* counts_mat = (int*)d_ws;                         // [nblk][MAXG]
    int* offsets    = counts_mat + (size_t)nblk * MAXG;   // [MAXG+1]
    int* cursor     = offsets + (MAXG + 1);               // [MAXG]
    float* xs       = (float*)(cursor + MAXG);            // [2*n_frag]
    int* bins       = (int*)(xs + 2 * (size_t)n_frag);    // [n_frag]
    size_t need = ((size_t)nblk * MAXG + (MAXG + 1) + MAXG
                   + 2 * (size_t)n_frag + (size_t)n_frag) * sizeof(int);

    bool use_sorted = (ws_size >= need) && (n_genes <= MAXG);
    if (use_sorted) {
        hist_init_k<<<nblk, HTPB, 0, stream>>>(gm, n_frag, n_genes, counts_mat,
                                               out, b2, genes_oi, gene_n, total);
        scan_k<<<1, MAXG, 0, stream>>>(counts_mat, nblk, offsets, cursor, n_genes);
        scatter_k<<<nblk, HTPB, 0, stream>>>(gm, coords, lcg, cursor,
                                             xs, bins, n_frag, n_genes);
        main_k<<<n_genes * SPLIT, 256, 0, stream>>>(w1, b1, w2, genes_oi, xs, bins,
                                                    offsets, out, gene_n);
    } else {
        init_out_k<<<(total + 255) / 256, 256, 0, stream>>>(out, b2, genes_oi, gene_n, total);
        frag_naive_k<<<(n_frag + 255) / 256, 256, 0, stream>>>(coords, w1, b1, w2, gm, lcg,
                                                               genes_oi, out, gene_n, n_frag);
    }
}

// Round 5
// 58.719 us; speedup vs baseline: 1.7761x; 1.0055x over previous
//
#include <hip/hip_runtime.h>
#include <hip/hip_bf16.h>
#include <math.h>

#define NF    50              // n_frequencies
#define DEMB  10              // embedding dim
#define W1G   (4 * NF * DEMB) // 2000 floats of w1 per gene
#define MAXG  512             // max genes supported by sort path

#define HTPB   256
#define HCHUNK 4096
#define HFPT   (HCHUNK / HTPB) // 16 fragments per thread in hist/scatter

// ---------------------------------------------------------------------------
// K1: per-block private histogram rows (no global atomics, no pre-zeroing
// needed: every row is fully overwritten each launch) + out init with b2
// ---------------------------------------------------------------------------
__global__ __launch_bounds__(HTPB) void hist_init_k(
    const int* __restrict__ gm, int n_frag, int n_genes,
    int* __restrict__ counts_mat,                 // [gridDim.x][MAXG]
    float* __restrict__ out, const float* __restrict__ b2,
    const int* __restrict__ genes_oi, int gene_n, int total)
{
    __shared__ int lcnt[MAXG];
    for (int t = threadIdx.x; t < MAXG; t += HTPB) lcnt[t] = 0;
    __syncthreads();

    int base = blockIdx.x * HCHUNK;
#pragma unroll
    for (int j = 0; j < HFPT; ++j) {
        int f = base + j * HTPB + (int)threadIdx.x;
        if (f < n_frag) atomicAdd(&lcnt[gm[f]], 1);
    }

    // init out with broadcast b2 (grid-stride; independent of hist)
    int nthreads = gridDim.x * HTPB;
    for (int i = blockIdx.x * HTPB + (int)threadIdx.x; i < total; i += nthreads) {
        int col = (int)((unsigned)i % (unsigned)gene_n);
        out[i] = b2[genes_oi[col]];
    }

    __syncthreads();
    int* row = counts_mat + (size_t)blockIdx.x * MAXG;
    for (int t = threadIdx.x; t < MAXG; t += HTPB) row[t] = lcnt[t];
}

// ---------------------------------------------------------------------------
// K2: reduce count matrix (coalesced columns, pipelined) + exclusive scan
// ---------------------------------------------------------------------------
__global__ void scan_k(const int* __restrict__ counts_mat, int nblk,
                       int* __restrict__ offsets, int* __restrict__ cursor, int n_genes)
{
    __shared__ int buf[MAXG];
    int tid = threadIdx.x;
    int s = 0;
#pragma unroll 8
    for (int b = 0; b < nblk; ++b) s += counts_mat[(size_t)b * MAXG + tid];
    buf[tid] = s;
    __syncthreads();
    for (int d = 1; d < MAXG; d <<= 1) {
        int t = (tid >= d) ? buf[tid - d] : 0;
        __syncthreads();
        buf[tid] += t;
        __syncthreads();
    }
    if (tid < n_genes) {
        int incl = buf[tid];
        offsets[tid + 1] = incl;
        cursor[tid] = incl - s;   // exclusive prefix
    }
    if (tid == 0) offsets[0] = 0;
}

// ---------------------------------------------------------------------------
// K3: scatter packed records (coords, bin) into gene-sorted compact order.
// LDS atomics assign local ranks; <=n_genes returning global atomics/block.
// ---------------------------------------------------------------------------
__global__ __launch_bounds__(HTPB) void scatter_k(
    const int* __restrict__ gm, const float* __restrict__ coords,
    const int* __restrict__ lcg, int* __restrict__ cursor,
    float* __restrict__ xs, int* __restrict__ bins,
    int n_frag, int n_genes)
{
    __shared__ int lcnt[MAXG];
    __shared__ int lbase[MAXG];
    for (int t = threadIdx.x; t < MAXG; t += HTPB) lcnt[t] = 0;
    __syncthreads();

    int base = blockIdx.x * HCHUNK;
    int g[HFPT], lr[HFPT];
#pragma unroll
    for (int j = 0; j < HFPT; ++j) {
        int f = base + j * HTPB + (int)threadIdx.x;
        if (f < n_frag) {
            g[j]  = gm[f];
            lr[j] = atomicAdd(&lcnt[g[j]], 1);
        } else {
            g[j] = -1;
        }
    }
    __syncthreads();
    for (int t = threadIdx.x; t < MAXG; t += HTPB) {
        int c = lcnt[t];
        lbase[t] = c ? atomicAdd(&cursor[t], c) : 0;
    }
    __syncthreads();
#pragma unroll
    for (int j = 0; j < HFPT; ++j) {
        if (g[j] >= 0) {
            int f = base + j * HTPB + (int)threadIdx.x;
            int pos = lbase[g[j]] + lr[j];
            float2 xy = ((const float2*)coords)[f];
            xs[2 * pos + 0] = xy.x;
            xs[2 * pos + 1] = xy.y;
            bins[pos] = lcg[f];
        }
    }
}

// ---------------------------------------------------------------------------
// K4: main — gene-PAIR per 256-thread block (128 threads per gene), weights
// staged in LDS (freq-major, padded to 12), F=4 fragments per thread so each
// broadcast ds_read is amortized over 4 fragments' FMAs.
// lw[h][i][slot][d]: slot 0/1 = sin/cos row of coord 0; 2/3 = coord 1.
// ---------------------------------------------------------------------------
__global__ __launch_bounds__(256) void main_k(
    const float* __restrict__ w1, const float* __restrict__ b1,
    const float* __restrict__ w2, const int* __restrict__ genes_oi,
    const float* __restrict__ xs, const int* __restrict__ bins,
    const int* __restrict__ offsets, float* __restrict__ out,
    int gene_n, int n_genes)
{
    __shared__ float fr[NF];
    __shared__ __align__(16) float lw[2][NF][4][12];
    __shared__ float lb1[2][DEMB];

    int gbase = 2 * blockIdx.x;

    if (threadIdx.x < NF) {
        float ex = (-2.0f * (float)(threadIdx.x + 1) / (float)NF) * 9.965784284662087f;
        fr[threadIdx.x] = exp2f(ex) * 0.15915494309189535f;  // base/(2*pi): revolutions
    }
    if (threadIdx.x < 2 * DEMB) {
        int hh = threadIdx.x / DEMB, d = threadIdx.x - hh * DEMB;
        int g = gbase + hh;
        lb1[hh][d] = (g < n_genes) ? b1[(size_t)g * DEMB + d] : 0.0f;
    }

    // stage + permute + pad both genes' w1 rows: 2 x 2400 floats
    for (int k = threadIdx.x; k < 2 * NF * 4 * 12; k += 256) {
        int hh   = k / (NF * 4 * 12);
        int rem  = k - hh * (NF * 4 * 12);
        int i    = rem / 48;
        int r2   = rem - i * 48;
        int slot = r2 / 12;
        int d    = r2 - slot * 12;
        int g    = gbase + hh;
        float v  = 0.0f;
        if (g < n_genes && d < DEMB) {
            int s = (slot < 2) ? (2 * i + slot) : (2 * NF + 2 * i + (slot - 2));
            v = w1[(size_t)g * W1G + s * DEMB + d];
        }
        (&lw[0][0][0][0])[k] = v;
    }
    __syncthreads();

    int half = threadIdx.x >> 7;          // which gene of the pair
    int tl   = threadIdx.x & 127;
    int g    = gbase + half;
    if (g >= n_genes) return;             // no barriers after this point

    int s0 = offsets[g], e0 = offsets[g + 1];

    for (int base = s0 + tl; base < e0; base += 4 * 128) {
        int  idx[4];
        bool val[4];
        float2 xy[4];
#pragma unroll
        for (int f = 0; f < 4; ++f) {
            idx[f] = base + f * 128;
            val[f] = idx[f] < e0;
            xy[f]  = val[f] ? ((const float2*)xs)[idx[f]] : make_float2(0.0f, 0.0f);
        }

        float h[4][DEMB];
#pragma unroll
        for (int f = 0; f < 4; ++f)
#pragma unroll
            for (int d = 0; d < DEMB; ++d) h[f][d] = lb1[half][d];

#pragma unroll 1
        for (int i = 0; i < NF; ++i) {
            float fv = fr[i];
            float sc[4][4];
#pragma unroll
            for (int f = 0; f < 4; ++f) {
                float r0 = xy[f].x * fv; r0 -= rintf(r0);
                float r1 = xy[f].y * fv; r1 -= rintf(r1);
                sc[f][0] = __builtin_amdgcn_sinf(r0);
                sc[f][1] = __builtin_amdgcn_cosf(r0);
                sc[f][2] = __builtin_amdgcn_sinf(r1);
                sc[f][3] = __builtin_amdgcn_cosf(r1);
            }
#pragma unroll
            for (int slot = 0; slot < 4; ++slot) {
                float4 a = *(const float4*)(&lw[half][i][slot][0]);
                float4 b = *(const float4*)(&lw[half][i][slot][4]);
                float2 c = *(const float2*)(&lw[half][i][slot][8]);
#pragma unroll
                for (int f = 0; f < 4; ++f) {
                    float sv = sc[f][slot];
                    h[f][0] += sv * a.x; h[f][1] += sv * a.y;
                    h[f][2] += sv * a.z; h[f][3] += sv * a.w;
                    h[f][4] += sv * b.x; h[f][5] += sv * b.y;
                    h[f][6] += sv * b.z; h[f][7] += sv * b.w;
                    h[f][8] += sv * c.x; h[f][9] += sv * c.y;
                }
            }
        }

#pragma unroll
        for (int f = 0; f < 4; ++f) {
            if (val[f]) {
                int bin = bins[idx[f]];
                int col = (int)((unsigned)bin % (unsigned)gene_n);
                const float* w2row = w2 + (size_t)genes_oi[col] * DEMB;
                float sum = 0.0f;
#pragma unroll
                for (int d = 0; d < DEMB; ++d) {
                    float sg = 1.0f / (1.0f + __expf(-h[f][d]));
                    sum += sg * w2row[d];
                }
                atomicAdd(&out[bin], sum);
            }
        }
    }
}

// ---------------------------------------------------------------------------
// Fallback (workspace too small): one thread per fragment, non-uniform gene
// ---------------------------------------------------------------------------
__global__ __launch_bounds__(256) void frag_naive_k(
    const float* __restrict__ coords, const float* __restrict__ w1,
    const float* __restrict__ b1, const float* __restrict__ w2,
    const int* __restrict__ gm, const int* __restrict__ lcg,
    const int* __restrict__ genes_oi, float* __restrict__ out,
    int gene_n, int n_frag)
{
    __shared__ float fr[NF];
    if (threadIdx.x < NF) {
        float ex = (-2.0f * (float)(threadIdx.x + 1) / (float)NF) * 9.965784284662087f;
        fr[threadIdx.x] = exp2f(ex) * 0.15915494309189535f;
    }
    __syncthreads();

    int f = blockIdx.x * blockDim.x + threadIdx.x;
    if (f >= n_frag) return;
    int g = gm[f];
    const float* wrow  = w1 + (size_t)g * W1G;
    const float* b1row = b1 + (size_t)g * DEMB;
    float x0 = coords[2 * f + 0];
    float x1 = coords[2 * f + 1];

    float h[DEMB];
#pragma unroll
    for (int d = 0; d < DEMB; ++d) h[d] = b1row[d];
#pragma unroll 2
    for (int i = 0; i < NF; ++i) {
        float fv = fr[i];
        float r0 = x0 * fv; r0 -= rintf(r0);
        float r1 = x1 * fv; r1 -= rintf(r1);
        float s0 = __builtin_amdgcn_sinf(r0), c0 = __builtin_amdgcn_cosf(r0);
        float s1 = __builtin_amdgcn_sinf(r1), c1 = __builtin_amdgcn_cosf(r1);
        const float* wa = wrow + (2 * i) * DEMB;
        const float* wb = wrow + (2 * NF + 2 * i) * DEMB;
#pragma unroll
        for (int d = 0; d < DEMB; ++d) {
            h[d] += s0 * wa[d] + c0 * wa[DEMB + d] + s1 * wb[d] + c1 * wb[DEMB + d];
        }
    }
    int bin = lcg[f];
    int col = (int)((unsigned)bin % (unsigned)gene_n);
    const float* w2row = w2 + (size_t)genes_oi[col] * DEMB;
    float sum = 0.0f;
#pragma unroll
    for (int d = 0; d < DEMB; ++d) {
        float sg = 1.0f / (1.0f + __expf(-h[d]));
        sum += sg * w2row[d];
    }
    atomicAdd(&out[bin], sum);
}

__global__ void init_out_k(float* __restrict__ out, const float* __restrict__ b2,
                           const int* __restrict__ genes_oi, int gene_n, int total)
{
    int i = blockIdx.x * blockDim.x + threadIdx.x;
    if (i < total) {
        int col = (int)((unsigned)i % (unsigned)gene_n);
        out[i] = b2[genes_oi[col]];
    }
}

// ---------------------------------------------------------------------------
extern "C" void kernel_launch(void* const* d_in, const int* in_sizes, int n_in,
                              void* d_out, int out_size, void* d_ws, size_t ws_size,
                              hipStream_t stream)
{
    const float* coords   = (const float*)d_in[0];
    const float* w1       = (const float*)d_in[1];
    const float* b1       = (const float*)d_in[2];
    const float* w2       = (const float*)d_in[3];
    const float* b2       = (const float*)d_in[4];
    const int*   gm       = (const int*)d_in[5];
    const int*   lcg      = (const int*)d_in[6];
    const int*   genes_oi = (const int*)d_in[7];

    int n_frag  = in_sizes[5];
    int n_genes = in_sizes[4];
    int gene_n  = in_sizes[7];
    int total   = out_size;
    float* out  = (float*)d_out;

    int nblk = (n_frag + HCHUNK - 1) / HCHUNK;

    // workspace layout
    int* counts_mat = (int*)d_ws;                         // [nblk][MAXG]
    int* offsets    = counts_mat + (size_t)nblk * MAXG;   // [MAXG+1]
    int* cursor     = offsets + (MAXG + 1);               // [MAXG]
    float* xs       = (float*)(cursor + MAXG);            // [2*n_frag]
    int* bins       = (int*)(xs + 2 * (size_t)n_frag);    // [n_frag]
    size_t need = ((size_t)nblk * MAXG + (MAXG + 1) + MAXG
                   + 2 * (size_t)n_frag + (size_t)n_frag) * sizeof(int);

    bool use_sorted = (ws_size >= need) && (n_genes <= MAXG);
    if (use_sorted) {
        hist_init_k<<<nblk, HTPB, 0, stream>>>(gm, n_frag, n_genes, counts_mat,
                                               out, b2, genes_oi, gene_n, total);
        scan_k<<<1, MAXG, 0, stream>>>(counts_mat, nblk, offsets, cursor, n_genes);
        scatter_k<<<nblk, HTPB, 0, stream>>>(gm, coords, lcg, cursor,
                                             xs, bins, n_frag, n_genes);
        int mblk = (n_genes + 1) / 2;
        main_k<<<mblk, 256, 0, stream>>>(w1, b1, w2, genes_oi, xs, bins,
                                         offsets, out, gene_n, n_genes);
    } else {
        init_out_k<<<(total + 255) / 256, 256, 0, stream>>>(out, b2, genes_oi, gene_n, total);
        frag_naive_k<<<(n_frag + 255) / 256, 256, 0, stream>>>(coords, w1, b1, w2, gm, lcg,
                                                               genes_oi, out, gene_n, n_frag);
    }
}